// Round 2
// baseline (517.858 us; speedup 1.0000x reference)
//
#include <hip/hip_runtime.h>
#include <hip/hip_bf16.h>

#define HDIM 1024
#define IDIM 768
#define NE   8
#define BT   64
#define BN   64
#define BK   32

typedef __attribute__((ext_vector_type(2))) float f32x2;

static __device__ __forceinline__ f32x2 pk_fma(f32x2 a, f32x2 b, f32x2 c) {
#if __has_builtin(__builtin_elementwise_fma)
    return __builtin_elementwise_fma(a, b, c);
#else
    f32x2 r; r.x = fmaf(a.x, b.x, c.x); r.y = fmaf(a.y, b.y, c.y); return r;
#endif
}

// ---------------- Router: logits -> top2 -> renormalized weights ----------------
// One wave (64 lanes) per token. Softmax denominator cancels under top-k renorm:
// w0 = 1/(1+e^{l1-l0}), w1 = 1-w0.
__global__ __launch_bounds__(256) void router_kernel(
    const float* __restrict__ x, const float* __restrict__ gate_w,
    int* __restrict__ counts, int* __restrict__ tok_list, float* __restrict__ w_list,
    int T)
{
    int wave = (blockIdx.x * blockDim.x + threadIdx.x) >> 6;
    int lane = threadIdx.x & 63;
    if (wave >= T) return;
    const float* xr = x + (size_t)wave * HDIM;

    float acc[NE];
    #pragma unroll
    for (int e = 0; e < NE; ++e) acc[e] = 0.f;

    for (int h = lane; h < HDIM; h += 64) {
        float xv = xr[h];
        const float* g = gate_w + (size_t)h * NE;
        #pragma unroll
        for (int e = 0; e < NE; ++e) acc[e] += xv * g[e];
    }
    #pragma unroll
    for (int e = 0; e < NE; ++e) {
        float v = acc[e];
        #pragma unroll
        for (int s = 32; s > 0; s >>= 1) v += __shfl_xor(v, s);
        acc[e] = v;
    }
    if (lane == 0) {
        // top-2 on logits (same order as softmax probs); strict > keeps lowest index on ties
        int e0 = 0;
        #pragma unroll
        for (int e = 1; e < NE; ++e) if (acc[e] > acc[e0]) e0 = e;
        int e1 = -1;
        #pragma unroll
        for (int e = 0; e < NE; ++e) {
            if (e == e0) continue;
            if (e1 < 0 || acc[e] > acc[e1]) e1 = e;
        }
        float d  = __expf(acc[e1] - acc[e0]);   // <= 1
        float w0 = 1.f / (1.f + d);
        float w1 = 1.f - w0;
        int p0 = atomicAdd(&counts[e0], 1);
        tok_list[e0 * T + p0] = wave;  w_list[e0 * T + p0] = w0;
        int p1 = atomicAdd(&counts[e1], 1);
        tok_list[e1 * T + p1] = wave;  w_list[e1 * T + p1] = w1;
    }
}

__global__ void prefix_kernel(const int* __restrict__ counts, int* __restrict__ offsets)
{
    if (threadIdx.x == 0 && blockIdx.x == 0) {
        int s = 0;
        for (int e = 0; e < NE; ++e) { offsets[e] = s; s += counts[e]; }
    }
}

// ---------------- Phase A: A = silu(X_e @ Wg_e) * (X_e @ Wu_e) ----------------
// Grid: (ceil(T/BT), IDIM/BN, NE). 256 threads, each computes 4x4 of G and U
// via packed f32x2 FMA (v_pk_fma_f32).
__global__ __launch_bounds__(256) void gateup_kernel(
    const float* __restrict__ x,
    const float* __restrict__ w_gate, const float* __restrict__ w_up,
    const int* __restrict__ counts, const int* __restrict__ offsets,
    const int* __restrict__ tok_list,
    float* __restrict__ Abuf, int T)
{
    int e = blockIdx.z;
    int n = counts[e];
    int t0 = blockIdx.x * BT;
    if (t0 >= n) return;
    int i0 = blockIdx.y * BN;

    __shared__ float Xs[BK][BT + 4];  // transposed: Xs[k][row]; +4 keeps b128 alignment
    __shared__ float Gs[BK][BN];
    __shared__ float Us[BK][BN];
    __shared__ int   toks[BT];

    int tid = threadIdx.x;
    if (tid < BT) {
        int r = t0 + tid;
        toks[tid] = (r < n) ? tok_list[e * T + r] : -1;
    }
    __syncthreads();

    int tx = tid & 15, ty = tid >> 4;
    f32x2 accg[4][2], accu[4][2];
    #pragma unroll
    for (int a = 0; a < 4; ++a)
        #pragma unroll
        for (int b = 0; b < 2; ++b) { accg[a][b] = (f32x2)0.f; accu[a][b] = (f32x2)0.f; }

    const float* wg = w_gate + (size_t)e * HDIM * IDIM;
    const float* wu = w_up   + (size_t)e * HDIM * IDIM;

    for (int k0 = 0; k0 < HDIM; k0 += BK) {
        // X tile: 64 rows x 32 k, float4 along k, scalar-scatter transposed into LDS
        #pragma unroll
        for (int j = 0; j < (BT * BK) / (256 * 4); ++j) {
            int idx = tid + j * 256;           // 0..511
            int r = idx >> 3, c4 = (idx & 7) * 4;
            int tok = toks[r];
            float4 v = (tok >= 0) ? *(const float4*)&x[(size_t)tok * HDIM + k0 + c4]
                                  : make_float4(0.f, 0.f, 0.f, 0.f);
            Xs[c4 + 0][r] = v.x; Xs[c4 + 1][r] = v.y;
            Xs[c4 + 2][r] = v.z; Xs[c4 + 3][r] = v.w;
        }
        // W tiles: 32 k x 64 i, float4 along i
        #pragma unroll
        for (int j = 0; j < (BK * BN) / (256 * 4); ++j) {
            int idx = tid + j * 256;           // 0..511
            int r = idx >> 4, c4 = (idx & 15) * 4;
            *(float4*)&Gs[r][c4] = *(const float4*)&wg[(size_t)(k0 + r) * IDIM + i0 + c4];
            *(float4*)&Us[r][c4] = *(const float4*)&wu[(size_t)(k0 + r) * IDIM + i0 + c4];
        }
        __syncthreads();
        #pragma unroll
        for (int kk = 0; kk < BK; ++kk) {
            float4 xf = *(const float4*)&Xs[kk][ty * 4];
            float4 gf = *(const float4*)&Gs[kk][tx * 4];
            float4 uf = *(const float4*)&Us[kk][tx * 4];
            f32x2 g0 = {gf.x, gf.y}, g1 = {gf.z, gf.w};
            f32x2 u0 = {uf.x, uf.y}, u1 = {uf.z, uf.w};
            float xv[4] = {xf.x, xf.y, xf.z, xf.w};
            #pragma unroll
            for (int a = 0; a < 4; ++a) {
                f32x2 xa = {xv[a], xv[a]};
                accg[a][0] = pk_fma(xa, g0, accg[a][0]);
                accg[a][1] = pk_fma(xa, g1, accg[a][1]);
                accu[a][0] = pk_fma(xa, u0, accu[a][0]);
                accu[a][1] = pk_fma(xa, u1, accu[a][1]);
            }
        }
        __syncthreads();
    }

    int base = offsets[e] + t0;
    #pragma unroll
    for (int a = 0; a < 4; ++a) {
        int r = ty * 4 + a;
        if (t0 + r < n) {
            float* arow = Abuf + (size_t)(base + r) * IDIM + i0 + tx * 4;
            float4 v;
            float gvals[4] = {accg[a][0].x, accg[a][0].y, accg[a][1].x, accg[a][1].y};
            float uvals[4] = {accu[a][0].x, accu[a][0].y, accu[a][1].x, accu[a][1].y};
            float* vv = &v.x;
            #pragma unroll
            for (int b = 0; b < 4; ++b) {
                float g = gvals[b];
                float s = g / (1.f + __expf(-g));   // silu
                vv[b] = s * uvals[b];
            }
            *(float4*)arow = v;
        }
    }
}

// ---------------- Phase B: out[t] += w * (A_e @ Wd_e) ----------------
// Grid: (ceil(T/BT), HDIM/BN, NE).
__global__ __launch_bounds__(256) void down_kernel(
    const float* __restrict__ Abuf,
    const float* __restrict__ w_down,
    const int* __restrict__ counts, const int* __restrict__ offsets,
    const int* __restrict__ tok_list, const float* __restrict__ w_list,
    float* __restrict__ out, int T)
{
    int e = blockIdx.z;
    int n = counts[e];
    int t0 = blockIdx.x * BT;
    if (t0 >= n) return;
    int h0 = blockIdx.y * BN;

    __shared__ float As[BK][BT + 4];  // transposed
    __shared__ float Ws[BK][BN];
    __shared__ int   toks[BT];
    __shared__ float wts[BT];

    int tid = threadIdx.x;
    if (tid < BT) {
        int r = t0 + tid;
        toks[tid] = (r < n) ? tok_list[e * T + r] : -1;
        wts[tid]  = (r < n) ? w_list[e * T + r] : 0.f;
    }
    __syncthreads();

    int tx = tid & 15, ty = tid >> 4;
    f32x2 acc[4][2];
    #pragma unroll
    for (int a = 0; a < 4; ++a)
        #pragma unroll
        for (int b = 0; b < 2; ++b) acc[a][b] = (f32x2)0.f;

    const float* wd = w_down + (size_t)e * IDIM * HDIM;
    int base = offsets[e] + t0;

    for (int k0 = 0; k0 < IDIM; k0 += BK) {
        #pragma unroll
        for (int j = 0; j < (BT * BK) / (256 * 4); ++j) {
            int idx = tid + j * 256;           // 0..511
            int r = idx >> 3, c4 = (idx & 7) * 4;
            float4 v = (t0 + r < n) ? *(const float4*)&Abuf[(size_t)(base + r) * IDIM + k0 + c4]
                                    : make_float4(0.f, 0.f, 0.f, 0.f);
            As[c4 + 0][r] = v.x; As[c4 + 1][r] = v.y;
            As[c4 + 2][r] = v.z; As[c4 + 3][r] = v.w;
        }
        #pragma unroll
        for (int j = 0; j < (BK * BN) / (256 * 4); ++j) {
            int idx = tid + j * 256;
            int r = idx >> 4, c4 = (idx & 15) * 4;
            *(float4*)&Ws[r][c4] = *(const float4*)&wd[(size_t)(k0 + r) * HDIM + h0 + c4];
        }
        __syncthreads();
        #pragma unroll
        for (int kk = 0; kk < BK; ++kk) {
            float4 af = *(const float4*)&As[kk][ty * 4];
            float4 wf = *(const float4*)&Ws[kk][tx * 4];
            f32x2 w0 = {wf.x, wf.y}, w1 = {wf.z, wf.w};
            float av[4] = {af.x, af.y, af.z, af.w};
            #pragma unroll
            for (int a = 0; a < 4; ++a) {
                f32x2 aa = {av[a], av[a]};
                acc[a][0] = pk_fma(aa, w0, acc[a][0]);
                acc[a][1] = pk_fma(aa, w1, acc[a][1]);
            }
        }
        __syncthreads();
    }

    #pragma unroll
    for (int a = 0; a < 4; ++a) {
        int r = ty * 4 + a;
        if (t0 + r < n) {
            int t = toks[r];
            float w = wts[r];
            float* orow = out + (size_t)t * HDIM + h0 + tx * 4;
            float vals[4] = {acc[a][0].x, acc[a][0].y, acc[a][1].x, acc[a][1].y};
            #pragma unroll
            for (int b = 0; b < 4; ++b)
                atomicAdd(&orow[b], w * vals[b]);
        }
    }
}

extern "C" void kernel_launch(void* const* d_in, const int* in_sizes, int n_in,
                              void* d_out, int out_size, void* d_ws, size_t ws_size,
                              hipStream_t stream)
{
    const float* x      = (const float*)d_in[0];
    const float* gate_w = (const float*)d_in[1];
    const float* w_gate = (const float*)d_in[2];
    const float* w_up   = (const float*)d_in[3];
    const float* w_down = (const float*)d_in[4];
    float* out = (float*)d_out;

    int T = in_sizes[0] / HDIM;   // 1024 for B=2,S=512

    // Workspace layout
    char* ws = (char*)d_ws;
    int*   counts   = (int*)ws;                               // 8 ints
    int*   offsets  = (int*)(ws + 32);                        // 8 ints
    int*   tok_list = (int*)(ws + 64);                        // NE*T ints
    float* w_list   = (float*)(ws + 64 + (size_t)NE * T * 4); // NE*T floats
    size_t abase    = 64 + (size_t)NE * T * 8;
    abase = (abase + 255) & ~(size_t)255;
    float* Abuf     = (float*)(ws + abase);                   // (T*2)*IDIM floats

    hipMemsetAsync(counts, 0, 32, stream);
    hipMemsetAsync(out, 0, (size_t)out_size * sizeof(float), stream);

    router_kernel<<<(T + 3) / 4, 256, 0, stream>>>(x, gate_w, counts, tok_list, w_list, T);
    prefix_kernel<<<1, 64, 0, stream>>>(counts, offsets);

    dim3 gridA((T + BT - 1) / BT, IDIM / BN, NE);
    gateup_kernel<<<gridA, 256, 0, stream>>>(x, w_gate, w_up, counts, offsets, tok_list, Abuf, T);

    dim3 gridB((T + BT - 1) / BT, HDIM / BN, NE);
    down_kernel<<<gridB, 256, 0, stream>>>(Abuf, w_down, counts, offsets, tok_list, w_list, out, T);
}

// Round 4
// 265.455 us; speedup vs baseline: 1.9508x; 1.9508x over previous
//
#include <hip/hip_runtime.h>
#include <hip/hip_bf16.h>

#define HDIM 1024
#define IDIM 768
#define NE   8

typedef __attribute__((ext_vector_type(8))) __bf16 bf16x8;
typedef __attribute__((ext_vector_type(4))) __bf16 bf16x4;
typedef __attribute__((ext_vector_type(4))) float  f32x4;

__device__ __forceinline__ void gload16(const void* g, void* l) {
    __builtin_amdgcn_global_load_lds(
        (const __attribute__((address_space(1))) void*)g,
        (__attribute__((address_space(3))) void*)l, 16, 0, 0);
}

// ---------------- Router: logits -> top2 -> renormalized weights ----------------
__global__ __launch_bounds__(256) void router_kernel(
    const float* __restrict__ x, const float* __restrict__ gate_w,
    int* __restrict__ counts, int* __restrict__ tok_list, float* __restrict__ w_list,
    int T)
{
    int wave = (blockIdx.x * blockDim.x + threadIdx.x) >> 6;
    int lane = threadIdx.x & 63;
    if (wave >= T) return;
    const float* xr = x + (size_t)wave * HDIM;

    float acc[NE];
    #pragma unroll
    for (int e = 0; e < NE; ++e) acc[e] = 0.f;

    for (int h = lane; h < HDIM; h += 64) {
        float xv = xr[h];
        const float* g = gate_w + (size_t)h * NE;
        #pragma unroll
        for (int e = 0; e < NE; ++e) acc[e] += xv * g[e];
    }
    #pragma unroll
    for (int e = 0; e < NE; ++e) {
        float v = acc[e];
        #pragma unroll
        for (int s = 32; s > 0; s >>= 1) v += __shfl_xor(v, s);
        acc[e] = v;
    }
    if (lane == 0) {
        int e0 = 0;
        #pragma unroll
        for (int e = 1; e < NE; ++e) if (acc[e] > acc[e0]) e0 = e;
        int e1 = -1;
        #pragma unroll
        for (int e = 0; e < NE; ++e) {
            if (e == e0) continue;
            if (e1 < 0 || acc[e] > acc[e1]) e1 = e;
        }
        float d  = __expf(acc[e1] - acc[e0]);   // <= 1
        float w0 = 1.f / (1.f + d);
        float w1 = 1.f - w0;
        int p0 = atomicAdd(&counts[e0], 1);
        tok_list[e0 * T + p0] = wave;  w_list[e0 * T + p0] = w0;
        int p1 = atomicAdd(&counts[e1], 1);
        tok_list[e1 * T + p1] = wave;  w_list[e1 * T + p1] = w1;
    }
}

__global__ void prefix_kernel(const int* __restrict__ counts, int* __restrict__ offsets)
{
    if (threadIdx.x == 0 && blockIdx.x == 0) {
        int s = 0;
        for (int e = 0; e < NE; ++e) { offsets[e] = s; s += counts[e]; }
    }
}

// ---------------- Gather x rows into sorted-slot order, fp32 -> bf16 ----------------
__global__ __launch_bounds__(256) void gather_x_kernel(
    const float* __restrict__ x, const int* __restrict__ offsets,
    const int* __restrict__ tok_list, const float* __restrict__ w_list,
    __bf16* __restrict__ xg, int* __restrict__ slot_tok, float* __restrict__ slot_w, int T)
{
    int s = (blockIdx.x * blockDim.x + threadIdx.x) >> 6;
    int lane = threadIdx.x & 63;
    if (s >= 2 * T) return;
    int e = 0;
    #pragma unroll
    for (int k = 1; k < NE; ++k) if (s >= offsets[k]) e = k;
    int pos = s - offsets[e];
    int tok = tok_list[e * T + pos];
    float w = w_list[e * T + pos];
    if (lane == 0) { slot_tok[s] = tok; slot_w[s] = w; }
    const float* xr = x + (size_t)tok * HDIM;
    __bf16* dr = xg + (size_t)s * HDIM;
    for (int j = lane * 4; j < HDIM; j += 256) {
        float4 v = *(const float4*)&xr[j];
        bf16x4 b;
        b[0] = (__bf16)v.x; b[1] = (__bf16)v.y; b[2] = (__bf16)v.z; b[3] = (__bf16)v.w;
        *(bf16x4*)&dr[j] = b;
    }
}

// ---------------- Transpose + convert: src fp32 [E][R][C] -> dst bf16 [E][C][R] ----------------
__global__ __launch_bounds__(256) void transpose_cvt_kernel(
    const float* __restrict__ src, __bf16* __restrict__ dst, int R, int C)
{
    int e = blockIdx.z;
    src += (size_t)e * R * C;
    dst += (size_t)e * R * C;
    int c0 = blockIdx.x * 64, r0 = blockIdx.y * 64;
    __shared__ __bf16 Lt[64][72];   // [c][r], padded
    int t = threadIdx.x;
    int rin = t >> 4, c4 = (t & 15) * 4;
    #pragma unroll
    for (int rr = 0; rr < 4; ++rr) {
        int r = rr * 16 + rin;
        float4 v = *(const float4*)&src[(size_t)(r0 + r) * C + c0 + c4];
        Lt[c4 + 0][r] = (__bf16)v.x; Lt[c4 + 1][r] = (__bf16)v.y;
        Lt[c4 + 2][r] = (__bf16)v.z; Lt[c4 + 3][r] = (__bf16)v.w;
    }
    __syncthreads();
    // 16 consecutive lanes write one contiguous 128B dst row (coalesced).
    int c = t >> 4, r4 = (t & 15) * 4;
    #pragma unroll
    for (int j = 0; j < 4; ++j) {
        int cc = c + j * 16;
        bf16x4 v = *(bf16x4*)&Lt[cc][r4];
        *(bf16x4*)&dst[(size_t)(c0 + cc) * R + r0 + r4] = v;
    }
}

// ---------------- Gate+Up MFMA: per expert, D[i][slot] tiles, silu(g)*u -> Abuf bf16 ----------
// A-operand = W^T [I][H] (rows i, contiguous k=h). B-operand = xg [slot][H] (cols slot, contiguous k).
// 64 slot x 64 i per block, 4 waves in 2x2, K-step 32, double-buffered global_load_lds.
__global__ __launch_bounds__(256) void gateup_mfma_kernel(
    const __bf16* __restrict__ xg,
    const __bf16* __restrict__ WgT, const __bf16* __restrict__ WuT,
    const int* __restrict__ counts, const int* __restrict__ offsets,
    __bf16* __restrict__ Abuf, int T)
{
    int e = blockIdx.z;
    int n = counts[e];
    int t0 = blockIdx.x * 64;
    if (t0 >= n) return;
    int i0 = blockIdx.y * 64;
    int base = offsets[e];

    __shared__ __bf16 lds[2][3][64 * 32];   // [buf][G,U,X][row*32+k] 24 KB

    int tid = threadIdx.x;
    int w = tid >> 6, lane = tid & 63;
    int wr = w >> 1, wc = w & 1;

    const __bf16* gW = WgT + (size_t)e * IDIM * HDIM;
    const __bf16* uW = WuT + (size_t)e * IDIM * HDIM;
    const __bf16* xS = xg + (size_t)(base + t0) * HDIM;

    // Staging: wave w loads tile rows 16w..16w+15; source chunk XOR-swizzled so
    // the linear global_load_lds dest yields a swizzled LDS tile (T2 both-sides rule).
    int srow = w * 16 + (lane >> 2);
    int swc  = (lane & 3) ^ ((srow >> 1) & 3);
    const __bf16* gsrc = gW + (size_t)(i0 + srow) * HDIM + swc * 8;
    const __bf16* usrc = uW + (size_t)(i0 + srow) * HDIM + swc * 8;
    const __bf16* xsrc = xS + (size_t)srow * HDIM + swc * 8;
    int ldsoff = w * 512;

    f32x4 accg[2][2], accu[2][2];
    #pragma unroll
    for (int a = 0; a < 2; ++a)
        #pragma unroll
        for (int b = 0; b < 2; ++b) { accg[a][b] = (f32x4)0.f; accu[a][b] = (f32x4)0.f; }

    int fr = lane & 15, fc = lane >> 4;
    int ra0 = wc * 32 + fr,  ra1 = ra0 + 16;   // weight (i) rows
    int rb0 = wr * 32 + fr,  rb1 = rb0 + 16;   // slot rows
    int offA0 = ra0 * 32 + ((fc ^ ((ra0 >> 1) & 3)) << 3);
    int offA1 = ra1 * 32 + ((fc ^ ((ra1 >> 1) & 3)) << 3);
    int offB0 = rb0 * 32 + ((fc ^ ((rb0 >> 1) & 3)) << 3);
    int offB1 = rb1 * 32 + ((fc ^ ((rb1 >> 1) & 3)) << 3);

    gload16(gsrc, &lds[0][0][ldsoff]);
    gload16(usrc, &lds[0][1][ldsoff]);
    gload16(xsrc, &lds[0][2][ldsoff]);

    const int NK = HDIM / 32;
    for (int kt = 0; kt < NK; ++kt) {
        int cur = kt & 1;
        __syncthreads();
        if (kt + 1 < NK) {
            int k0 = (kt + 1) * 32;
            gload16(gsrc + k0, &lds[cur ^ 1][0][ldsoff]);
            gload16(usrc + k0, &lds[cur ^ 1][1][ldsoff]);
            gload16(xsrc + k0, &lds[cur ^ 1][2][ldsoff]);
        }
        const __bf16* Lg = lds[cur][0];
        const __bf16* Lu = lds[cur][1];
        const __bf16* Lx = lds[cur][2];
        bf16x8 ag0 = *(const bf16x8*)(Lg + offA0);
        bf16x8 ag1 = *(const bf16x8*)(Lg + offA1);
        bf16x8 au0 = *(const bf16x8*)(Lu + offA0);
        bf16x8 au1 = *(const bf16x8*)(Lu + offA1);
        bf16x8 bx0 = *(const bf16x8*)(Lx + offB0);
        bf16x8 bx1 = *(const bf16x8*)(Lx + offB1);
        accg[0][0] = __builtin_amdgcn_mfma_f32_16x16x32_bf16(ag0, bx0, accg[0][0], 0, 0, 0);
        accg[0][1] = __builtin_amdgcn_mfma_f32_16x16x32_bf16(ag1, bx0, accg[0][1], 0, 0, 0);
        accg[1][0] = __builtin_amdgcn_mfma_f32_16x16x32_bf16(ag0, bx1, accg[1][0], 0, 0, 0);
        accg[1][1] = __builtin_amdgcn_mfma_f32_16x16x32_bf16(ag1, bx1, accg[1][1], 0, 0, 0);
        accu[0][0] = __builtin_amdgcn_mfma_f32_16x16x32_bf16(au0, bx0, accu[0][0], 0, 0, 0);
        accu[0][1] = __builtin_amdgcn_mfma_f32_16x16x32_bf16(au1, bx0, accu[0][1], 0, 0, 0);
        accu[1][0] = __builtin_amdgcn_mfma_f32_16x16x32_bf16(au0, bx1, accu[1][0], 0, 0, 0);
        accu[1][1] = __builtin_amdgcn_mfma_f32_16x16x32_bf16(au1, bx1, accu[1][1], 0, 0, 0);
    }

    // D: col = lane&15 = slot, row = (lane>>4)*4+reg = i (m89-verified layout)
    int dr4 = (lane >> 4) * 4;
    #pragma unroll
    for (int ti = 0; ti < 2; ++ti) {
        int tl = wr * 32 + ti * 16 + fr;
        if (t0 + tl < n) {
            size_t slotrow = (size_t)(base + t0 + tl) * IDIM;
            #pragma unroll
            for (int ii = 0; ii < 2; ++ii) {
                f32x4 g = accg[ti][ii], u = accu[ti][ii];
                bf16x4 o;
                #pragma unroll
                for (int r = 0; r < 4; ++r) {
                    float gv = g[r];
                    float s = gv / (1.f + __expf(-gv));
                    o[r] = (__bf16)(s * u[r]);
                }
                *(bf16x4*)&Abuf[slotrow + i0 + wc * 32 + ii * 16 + dr4] = o;
            }
        }
    }
}

// ---------------- Down MFMA: D[h][slot], weighted atomic scatter into out ----------------
__global__ __launch_bounds__(256) void down_mfma_kernel(
    const __bf16* __restrict__ Abuf, const __bf16* __restrict__ WdT,
    const int* __restrict__ counts, const int* __restrict__ offsets,
    const int* __restrict__ slot_tok, const float* __restrict__ slot_w,
    float* __restrict__ out, int T)
{
    int e = blockIdx.z;
    int n = counts[e];
    int t0 = blockIdx.x * 64;
    if (t0 >= n) return;
    int h0 = blockIdx.y * 64;
    int base = offsets[e];

    __shared__ __bf16 lds[2][2][64 * 32];   // [buf][W,A] 16 KB

    int tid = threadIdx.x;
    int w = tid >> 6, lane = tid & 63;
    int wr = w >> 1, wc = w & 1;

    const __bf16* dW = WdT + (size_t)e * HDIM * IDIM;   // [H][I]
    const __bf16* aS = Abuf + (size_t)(base + t0) * IDIM;

    int srow = w * 16 + (lane >> 2);
    int swc  = (lane & 3) ^ ((srow >> 1) & 3);
    const __bf16* wsrc = dW + (size_t)(h0 + srow) * IDIM + swc * 8;
    const __bf16* asrc = aS + (size_t)srow * IDIM + swc * 8;
    int ldsoff = w * 512;

    f32x4 acc[2][2];
    #pragma unroll
    for (int a = 0; a < 2; ++a)
        #pragma unroll
        for (int b = 0; b < 2; ++b) acc[a][b] = (f32x4)0.f;

    int fr = lane & 15, fc = lane >> 4;
    int ra0 = wc * 32 + fr,  ra1 = ra0 + 16;   // h rows
    int rb0 = wr * 32 + fr,  rb1 = rb0 + 16;   // slot rows
    int offA0 = ra0 * 32 + ((fc ^ ((ra0 >> 1) & 3)) << 3);
    int offA1 = ra1 * 32 + ((fc ^ ((ra1 >> 1) & 3)) << 3);
    int offB0 = rb0 * 32 + ((fc ^ ((rb0 >> 1) & 3)) << 3);
    int offB1 = rb1 * 32 + ((fc ^ ((rb1 >> 1) & 3)) << 3);

    gload16(wsrc, &lds[0][0][ldsoff]);
    gload16(asrc, &lds[0][1][ldsoff]);

    const int NK = IDIM / 32;
    for (int kt = 0; kt < NK; ++kt) {
        int cur = kt & 1;
        __syncthreads();
        if (kt + 1 < NK) {
            int k0 = (kt + 1) * 32;
            gload16(wsrc + k0, &lds[cur ^ 1][0][ldsoff]);
            gload16(asrc + k0, &lds[cur ^ 1][1][ldsoff]);
        }
        const __bf16* Lw = lds[cur][0];
        const __bf16* La = lds[cur][1];
        bf16x8 aw0 = *(const bf16x8*)(Lw + offA0);
        bf16x8 aw1 = *(const bf16x8*)(Lw + offA1);
        bf16x8 ab0 = *(const bf16x8*)(La + offB0);
        bf16x8 ab1 = *(const bf16x8*)(La + offB1);
        acc[0][0] = __builtin_amdgcn_mfma_f32_16x16x32_bf16(aw0, ab0, acc[0][0], 0, 0, 0);
        acc[0][1] = __builtin_amdgcn_mfma_f32_16x16x32_bf16(aw1, ab0, acc[0][1], 0, 0, 0);
        acc[1][0] = __builtin_amdgcn_mfma_f32_16x16x32_bf16(aw0, ab1, acc[1][0], 0, 0, 0);
        acc[1][1] = __builtin_amdgcn_mfma_f32_16x16x32_bf16(aw1, ab1, acc[1][1], 0, 0, 0);
    }

    int dr4 = (lane >> 4) * 4;
    #pragma unroll
    for (int si = 0; si < 2; ++si) {
        int sl = wr * 32 + si * 16 + fr;
        if (t0 + sl < n) {
            int slot = base + t0 + sl;
            int tok = slot_tok[slot];
            float wgt = slot_w[slot];
            float* orow = out + (size_t)tok * HDIM + h0;
            #pragma unroll
            for (int hi = 0; hi < 2; ++hi) {
                f32x4 a = acc[si][hi];
                int hb = wc * 32 + hi * 16 + dr4;
                #pragma unroll
                for (int r = 0; r < 4; ++r)
                    atomicAdd(&orow[hb + r], wgt * a[r]);
            }
        }
    }
}

extern "C" void kernel_launch(void* const* d_in, const int* in_sizes, int n_in,
                              void* d_out, int out_size, void* d_ws, size_t ws_size,
                              hipStream_t stream)
{
    const float* x      = (const float*)d_in[0];
    const float* gate_w = (const float*)d_in[1];
    const float* w_gate = (const float*)d_in[2];
    const float* w_up   = (const float*)d_in[3];
    const float* w_down = (const float*)d_in[4];
    float* out = (float*)d_out;

    int T = in_sizes[0] / HDIM;

    // Workspace layout (bytes), 256-aligned sections
    char* ws = (char*)d_ws;
    size_t o = 0;
    int* counts  = (int*)(ws + o); o += 32;
    int* offsets = (int*)(ws + o); o += 32;
    int* tok_list = (int*)(ws + o); o += (size_t)NE * T * 4;
    float* w_list = (float*)(ws + o); o += (size_t)NE * T * 4;
    o = (o + 255) & ~(size_t)255;
    int* slot_tok = (int*)(ws + o); o += (size_t)2 * T * 4;
    float* slot_w = (float*)(ws + o); o += (size_t)2 * T * 4;
    o = (o + 255) & ~(size_t)255;
    __bf16* xg = (__bf16*)(ws + o);   o += (size_t)(2 * T + 64) * HDIM * 2;
    o = (o + 255) & ~(size_t)255;
    __bf16* Abuf = (__bf16*)(ws + o); o += (size_t)(2 * T + 64) * IDIM * 2;
    o = (o + 255) & ~(size_t)255;
    __bf16* WgT = (__bf16*)(ws + o);  o += (size_t)NE * IDIM * HDIM * 2;
    __bf16* WuT = (__bf16*)(ws + o);  o += (size_t)NE * IDIM * HDIM * 2;
    __bf16* WdT = (__bf16*)(ws + o);  o += (size_t)NE * HDIM * IDIM * 2;

    hipMemsetAsync(counts, 0, 32, stream);
    hipMemsetAsync(out, 0, (size_t)out_size * sizeof(float), stream);

    router_kernel<<<(T + 3) / 4, 256, 0, stream>>>(x, gate_w, counts, tok_list, w_list, T);
    prefix_kernel<<<1, 64, 0, stream>>>(counts, offsets);
    gather_x_kernel<<<(2 * T + 3) / 4, 256, 0, stream>>>(x, offsets, tok_list, w_list,
                                                         xg, slot_tok, slot_w, T);

    transpose_cvt_kernel<<<dim3(IDIM / 64, HDIM / 64, NE), 256, 0, stream>>>(w_gate, WgT, HDIM, IDIM);
    transpose_cvt_kernel<<<dim3(IDIM / 64, HDIM / 64, NE), 256, 0, stream>>>(w_up,   WuT, HDIM, IDIM);
    transpose_cvt_kernel<<<dim3(HDIM / 64, IDIM / 64, NE), 256, 0, stream>>>(w_down, WdT, IDIM, HDIM);

    dim3 gridA((T + 63) / 64, IDIM / 64, NE);
    gateup_mfma_kernel<<<gridA, 256, 0, stream>>>(xg, WgT, WuT, counts, offsets, Abuf, T);

    dim3 gridB((T + 63) / 64, HDIM / 64, NE);
    down_mfma_kernel<<<gridB, 256, 0, stream>>>(Abuf, WdT, counts, offsets,
                                                slot_tok, slot_w, out, T);
}

// Round 5
// 241.719 us; speedup vs baseline: 2.1424x; 1.0982x over previous
//
#include <hip/hip_runtime.h>
#include <hip/hip_bf16.h>

#define HDIM 1024
#define IDIM 768
#define NE   8

typedef __attribute__((ext_vector_type(8))) __bf16 bf16x8;
typedef __attribute__((ext_vector_type(4))) __bf16 bf16x4;
typedef __attribute__((ext_vector_type(4))) float  f32x4;

__device__ __forceinline__ void gload16(const void* g, void* l) {
    __builtin_amdgcn_global_load_lds(
        (const __attribute__((address_space(1))) void*)g,
        (__attribute__((address_space(3))) void*)l, 16, 0, 0);
}

// ---------------- Router: logits -> top2 -> renormalized weights ----------------
__global__ __launch_bounds__(256) void router_kernel(
    const float* __restrict__ x, const float* __restrict__ gate_w,
    int* __restrict__ counts, int* __restrict__ tok_list,
    int* __restrict__ sel_e, int* __restrict__ sel_pos, float* __restrict__ sel_w,
    int T)
{
    int wave = (blockIdx.x * blockDim.x + threadIdx.x) >> 6;
    int lane = threadIdx.x & 63;
    if (wave >= T) return;
    const float* xr = x + (size_t)wave * HDIM;

    float acc[NE];
    #pragma unroll
    for (int e = 0; e < NE; ++e) acc[e] = 0.f;

    for (int h = lane; h < HDIM; h += 64) {
        float xv = xr[h];
        const float* g = gate_w + (size_t)h * NE;
        #pragma unroll
        for (int e = 0; e < NE; ++e) acc[e] += xv * g[e];
    }
    #pragma unroll
    for (int e = 0; e < NE; ++e) {
        float v = acc[e];
        #pragma unroll
        for (int s = 32; s > 0; s >>= 1) v += __shfl_xor(v, s);
        acc[e] = v;
    }
    if (lane == 0) {
        int e0 = 0;
        #pragma unroll
        for (int e = 1; e < NE; ++e) if (acc[e] > acc[e0]) e0 = e;
        int e1 = -1;
        #pragma unroll
        for (int e = 0; e < NE; ++e) {
            if (e == e0) continue;
            if (e1 < 0 || acc[e] > acc[e1]) e1 = e;
        }
        float d  = __expf(acc[e1] - acc[e0]);   // <= 1
        float w0 = 1.f / (1.f + d);
        float w1 = 1.f - w0;
        int p0 = atomicAdd(&counts[e0], 1);
        tok_list[e0 * T + p0] = wave;
        int p1 = atomicAdd(&counts[e1], 1);
        tok_list[e1 * T + p1] = wave;
        sel_e[wave * 2 + 0] = e0;  sel_pos[wave * 2 + 0] = p0;  sel_w[wave * 2 + 0] = w0;
        sel_e[wave * 2 + 1] = e1;  sel_pos[wave * 2 + 1] = p1;  sel_w[wave * 2 + 1] = w1;
    }
}

__global__ void prefix_kernel(const int* __restrict__ counts, int* __restrict__ offsets)
{
    if (threadIdx.x == 0 && blockIdx.x == 0) {
        int s = 0;
        for (int e = 0; e < NE; ++e) { offsets[e] = s; s += counts[e]; }
    }
}

// ---------------- Gather x rows into sorted-slot order, fp32 -> bf16 ----------------
__global__ __launch_bounds__(256) void gather_x_kernel(
    const float* __restrict__ x, const int* __restrict__ offsets,
    const int* __restrict__ tok_list, __bf16* __restrict__ xg, int T)
{
    int s = (blockIdx.x * blockDim.x + threadIdx.x) >> 6;
    int lane = threadIdx.x & 63;
    if (s >= 2 * T) return;
    int e = 0;
    #pragma unroll
    for (int k = 1; k < NE; ++k) if (s >= offsets[k]) e = k;
    int pos = s - offsets[e];
    int tok = tok_list[e * T + pos];
    const float* xr = x + (size_t)tok * HDIM;
    __bf16* dr = xg + (size_t)s * HDIM;
    for (int j = lane * 4; j < HDIM; j += 256) {
        float4 v = *(const float4*)&xr[j];
        bf16x4 b;
        b[0] = (__bf16)v.x; b[1] = (__bf16)v.y; b[2] = (__bf16)v.z; b[3] = (__bf16)v.w;
        *(bf16x4*)&dr[j] = b;
    }
}

// ---------------- Transpose + convert: src fp32 [E][R][C] -> dst bf16 [E][C][R] ----------------
__global__ __launch_bounds__(256) void transpose_cvt_kernel(
    const float* __restrict__ src, __bf16* __restrict__ dst, int R, int C)
{
    int e = blockIdx.z;
    src += (size_t)e * R * C;
    dst += (size_t)e * R * C;
    int c0 = blockIdx.x * 64, r0 = blockIdx.y * 64;
    __shared__ __bf16 Lt[64][72];   // [c][r], padded
    int t = threadIdx.x;
    int rin = t >> 4, c4 = (t & 15) * 4;
    #pragma unroll
    for (int rr = 0; rr < 4; ++rr) {
        int r = rr * 16 + rin;
        float4 v = *(const float4*)&src[(size_t)(r0 + r) * C + c0 + c4];
        Lt[c4 + 0][r] = (__bf16)v.x; Lt[c4 + 1][r] = (__bf16)v.y;
        Lt[c4 + 2][r] = (__bf16)v.z; Lt[c4 + 3][r] = (__bf16)v.w;
    }
    __syncthreads();
    // 16 consecutive lanes write one contiguous 128B dst row (coalesced).
    int c = t >> 4, r4 = (t & 15) * 4;
    #pragma unroll
    for (int j = 0; j < 4; ++j) {
        int cc = c + j * 16;
        bf16x4 v = *(bf16x4*)&Lt[cc][r4];
        *(bf16x4*)&dst[(size_t)(c0 + cc) * R + r0 + r4] = v;
    }
}

// ---------------- Gate+Up MFMA: D[i][slot], silu(g)*u -> Abuf bf16 ----------------
// 4-buffer ring, issue tile kt+3 each iter, counted vmcnt (never 0 mid-loop).
__global__ __launch_bounds__(256) void gateup_mfma_kernel(
    const __bf16* __restrict__ xg,
    const __bf16* __restrict__ WgT, const __bf16* __restrict__ WuT,
    const int* __restrict__ counts, const int* __restrict__ offsets,
    __bf16* __restrict__ Abuf, int T)
{
    int e = blockIdx.z;
    int n = counts[e];
    int t0 = blockIdx.x * 64;
    if (t0 >= n) return;
    int i0 = blockIdx.y * 64;
    int base = offsets[e];

    __shared__ __bf16 lds[4][3][64 * 32];   // [buf][G,U,X] 48 KB

    int tid = threadIdx.x;
    int w = tid >> 6, lane = tid & 63;
    int wr = w >> 1, wc = w & 1;

    const __bf16* gW = WgT + (size_t)e * IDIM * HDIM;
    const __bf16* uW = WuT + (size_t)e * IDIM * HDIM;
    const __bf16* xS = xg + (size_t)(base + t0) * HDIM;

    // Wave w stages rows 16w..16w+15; source XOR-pre-swizzled (T2 both-sides).
    int srow = w * 16 + (lane >> 2);
    int swc  = (lane & 3) ^ ((srow >> 1) & 3);
    const __bf16* gsrc = gW + (size_t)(i0 + srow) * HDIM + swc * 8;
    const __bf16* usrc = uW + (size_t)(i0 + srow) * HDIM + swc * 8;
    const __bf16* xsrc = xS + (size_t)srow * HDIM + swc * 8;
    int ldsoff = w * 512;

    f32x4 accg[2][2], accu[2][2];
    #pragma unroll
    for (int a = 0; a < 2; ++a)
        #pragma unroll
        for (int b = 0; b < 2; ++b) { accg[a][b] = (f32x4)0.f; accu[a][b] = (f32x4)0.f; }

    int fr = lane & 15, fc = lane >> 4;
    int ra0 = wc * 32 + fr,  ra1 = ra0 + 16;   // weight (i) rows
    int rb0 = wr * 32 + fr,  rb1 = rb0 + 16;   // slot rows
    int offA0 = ra0 * 32 + ((fc ^ ((ra0 >> 1) & 3)) << 3);
    int offA1 = ra1 * 32 + ((fc ^ ((ra1 >> 1) & 3)) << 3);
    int offB0 = rb0 * 32 + ((fc ^ ((rb0 >> 1) & 3)) << 3);
    int offB1 = rb1 * 32 + ((fc ^ ((rb1 >> 1) & 3)) << 3);

    const int NK = HDIM / 32;
    #pragma unroll
    for (int p = 0; p < 3; ++p) {
        int k0 = p * 32;
        gload16(gsrc + k0, &lds[p][0][ldsoff]);
        gload16(usrc + k0, &lds[p][1][ldsoff]);
        gload16(xsrc + k0, &lds[p][2][ldsoff]);
    }

    for (int kt = 0; kt < NK; ++kt) {
        int rem = NK - 1 - kt;
        if (rem >= 2)      asm volatile("s_waitcnt vmcnt(6)" ::: "memory");
        else if (rem == 1) asm volatile("s_waitcnt vmcnt(3)" ::: "memory");
        else               asm volatile("s_waitcnt vmcnt(0)" ::: "memory");
        __builtin_amdgcn_s_barrier();
        if (kt + 3 < NK) {
            int k0 = (kt + 3) * 32;
            int b = (kt + 3) & 3;
            gload16(gsrc + k0, &lds[b][0][ldsoff]);
            gload16(usrc + k0, &lds[b][1][ldsoff]);
            gload16(xsrc + k0, &lds[b][2][ldsoff]);
        }
        int cur = kt & 3;
        const __bf16* Lg = lds[cur][0];
        const __bf16* Lu = lds[cur][1];
        const __bf16* Lx = lds[cur][2];
        bf16x8 ag0 = *(const bf16x8*)(Lg + offA0);
        bf16x8 ag1 = *(const bf16x8*)(Lg + offA1);
        bf16x8 au0 = *(const bf16x8*)(Lu + offA0);
        bf16x8 au1 = *(const bf16x8*)(Lu + offA1);
        bf16x8 bx0 = *(const bf16x8*)(Lx + offB0);
        bf16x8 bx1 = *(const bf16x8*)(Lx + offB1);
        accg[0][0] = __builtin_amdgcn_mfma_f32_16x16x32_bf16(ag0, bx0, accg[0][0], 0, 0, 0);
        accg[0][1] = __builtin_amdgcn_mfma_f32_16x16x32_bf16(ag1, bx0, accg[0][1], 0, 0, 0);
        accg[1][0] = __builtin_amdgcn_mfma_f32_16x16x32_bf16(ag0, bx1, accg[1][0], 0, 0, 0);
        accg[1][1] = __builtin_amdgcn_mfma_f32_16x16x32_bf16(ag1, bx1, accg[1][1], 0, 0, 0);
        accu[0][0] = __builtin_amdgcn_mfma_f32_16x16x32_bf16(au0, bx0, accu[0][0], 0, 0, 0);
        accu[0][1] = __builtin_amdgcn_mfma_f32_16x16x32_bf16(au1, bx0, accu[0][1], 0, 0, 0);
        accu[1][0] = __builtin_amdgcn_mfma_f32_16x16x32_bf16(au0, bx1, accu[1][0], 0, 0, 0);
        accu[1][1] = __builtin_amdgcn_mfma_f32_16x16x32_bf16(au1, bx1, accu[1][1], 0, 0, 0);
    }

    // D: col = lane&15 = slot, row = (lane>>4)*4+reg = i
    int dr4 = (lane >> 4) * 4;
    #pragma unroll
    for (int ti = 0; ti < 2; ++ti) {
        int tl = wr * 32 + ti * 16 + fr;
        if (t0 + tl < n) {
            size_t slotrow = (size_t)(base + t0 + tl) * IDIM;
            #pragma unroll
            for (int ii = 0; ii < 2; ++ii) {
                f32x4 g = accg[ti][ii], u = accu[ti][ii];
                bf16x4 o;
                #pragma unroll
                for (int r = 0; r < 4; ++r) {
                    float gv = g[r];
                    float s = gv / (1.f + __expf(-gv));
                    o[r] = (__bf16)(s * u[r]);
                }
                *(bf16x4*)&Abuf[slotrow + i0 + wc * 32 + ii * 16 + dr4] = o;
            }
        }
    }
}

// ---------------- Down MFMA: Y[slot][h] = A_slot . Wd (fp32, contiguous) ----------------
__global__ __launch_bounds__(256) void down_mfma_kernel(
    const __bf16* __restrict__ Abuf, const __bf16* __restrict__ WdT,
    const int* __restrict__ counts, const int* __restrict__ offsets,
    float* __restrict__ Y, int T)
{
    int e = blockIdx.z;
    int n = counts[e];
    int t0 = blockIdx.x * 64;
    if (t0 >= n) return;
    int h0 = blockIdx.y * 64;
    int base = offsets[e];

    __shared__ __bf16 lds[4][2][64 * 32];   // 32 KB

    int tid = threadIdx.x;
    int w = tid >> 6, lane = tid & 63;
    int wr = w >> 1, wc = w & 1;

    const __bf16* dW = WdT + (size_t)e * HDIM * IDIM;   // [H][I]
    const __bf16* aS = Abuf + (size_t)(base + t0) * IDIM;

    int srow = w * 16 + (lane >> 2);
    int swc  = (lane & 3) ^ ((srow >> 1) & 3);
    const __bf16* wsrc = dW + (size_t)(h0 + srow) * IDIM + swc * 8;
    const __bf16* asrc = aS + (size_t)srow * IDIM + swc * 8;
    int ldsoff = w * 512;

    f32x4 acc[2][2];
    #pragma unroll
    for (int a = 0; a < 2; ++a)
        #pragma unroll
        for (int b = 0; b < 2; ++b) acc[a][b] = (f32x4)0.f;

    int fr = lane & 15, fc = lane >> 4;
    int ra0 = wc * 32 + fr,  ra1 = ra0 + 16;   // h rows
    int rb0 = wr * 32 + fr,  rb1 = rb0 + 16;   // slot rows
    int offA0 = ra0 * 32 + ((fc ^ ((ra0 >> 1) & 3)) << 3);
    int offA1 = ra1 * 32 + ((fc ^ ((ra1 >> 1) & 3)) << 3);
    int offB0 = rb0 * 32 + ((fc ^ ((rb0 >> 1) & 3)) << 3);
    int offB1 = rb1 * 32 + ((fc ^ ((rb1 >> 1) & 3)) << 3);

    const int NK = IDIM / 32;
    #pragma unroll
    for (int p = 0; p < 3; ++p) {
        int k0 = p * 32;
        gload16(wsrc + k0, &lds[p][0][ldsoff]);
        gload16(asrc + k0, &lds[p][1][ldsoff]);
    }

    for (int kt = 0; kt < NK; ++kt) {
        int rem = NK - 1 - kt;
        if (rem >= 2)      asm volatile("s_waitcnt vmcnt(4)" ::: "memory");
        else if (rem == 1) asm volatile("s_waitcnt vmcnt(2)" ::: "memory");
        else               asm volatile("s_waitcnt vmcnt(0)" ::: "memory");
        __builtin_amdgcn_s_barrier();
        if (kt + 3 < NK) {
            int k0 = (kt + 3) * 32;
            int b = (kt + 3) & 3;
            gload16(wsrc + k0, &lds[b][0][ldsoff]);
            gload16(asrc + k0, &lds[b][1][ldsoff]);
        }
        int cur = kt & 3;
        const __bf16* Lw = lds[cur][0];
        const __bf16* La = lds[cur][1];
        bf16x8 aw0 = *(const bf16x8*)(Lw + offA0);
        bf16x8 aw1 = *(const bf16x8*)(Lw + offA1);
        bf16x8 ab0 = *(const bf16x8*)(La + offB0);
        bf16x8 ab1 = *(const bf16x8*)(La + offB1);
        acc[0][0] = __builtin_amdgcn_mfma_f32_16x16x32_bf16(aw0, ab0, acc[0][0], 0, 0, 0);
        acc[0][1] = __builtin_amdgcn_mfma_f32_16x16x32_bf16(aw1, ab0, acc[0][1], 0, 0, 0);
        acc[1][0] = __builtin_amdgcn_mfma_f32_16x16x32_bf16(aw0, ab1, acc[1][0], 0, 0, 0);
        acc[1][1] = __builtin_amdgcn_mfma_f32_16x16x32_bf16(aw1, ab1, acc[1][1], 0, 0, 0);
    }

    int dr4 = (lane >> 4) * 4;
    #pragma unroll
    for (int si = 0; si < 2; ++si) {
        int sl = wr * 32 + si * 16 + fr;
        if (t0 + sl < n) {
            float* yrow = Y + (size_t)(base + t0 + sl) * HDIM + h0;
            #pragma unroll
            for (int hi = 0; hi < 2; ++hi) {
                f32x4 a = acc[si][hi];
                *(f32x4*)&yrow[wc * 32 + hi * 16 + dr4] = a;
            }
        }
    }
}

// ---------------- Combine: out[t] = w0*Y[s0] + w1*Y[s1] ----------------
__global__ __launch_bounds__(256) void combine_kernel(
    const float* __restrict__ Y, const int* __restrict__ offsets,
    const int* __restrict__ sel_e, const int* __restrict__ sel_pos,
    const float* __restrict__ sel_w, float* __restrict__ out)
{
    int t = blockIdx.x;
    int h4 = threadIdx.x * 4;            // 256 threads * 4 = 1024 = HDIM
    int s0 = offsets[sel_e[t * 2 + 0]] + sel_pos[t * 2 + 0];
    int s1 = offsets[sel_e[t * 2 + 1]] + sel_pos[t * 2 + 1];
    float w0 = sel_w[t * 2 + 0], w1 = sel_w[t * 2 + 1];
    float4 a = *(const float4*)&Y[(size_t)s0 * HDIM + h4];
    float4 b = *(const float4*)&Y[(size_t)s1 * HDIM + h4];
    float4 o;
    o.x = w0 * a.x + w1 * b.x;  o.y = w0 * a.y + w1 * b.y;
    o.z = w0 * a.z + w1 * b.z;  o.w = w0 * a.w + w1 * b.w;
    *(float4*)&out[(size_t)t * HDIM + h4] = o;
}

extern "C" void kernel_launch(void* const* d_in, const int* in_sizes, int n_in,
                              void* d_out, int out_size, void* d_ws, size_t ws_size,
                              hipStream_t stream)
{
    const float* x      = (const float*)d_in[0];
    const float* gate_w = (const float*)d_in[1];
    const float* w_gate = (const float*)d_in[2];
    const float* w_up   = (const float*)d_in[3];
    const float* w_down = (const float*)d_in[4];
    float* out = (float*)d_out;

    int T = in_sizes[0] / HDIM;

    // Workspace layout (bytes), 256-aligned sections
    char* ws = (char*)d_ws;
    size_t o = 0;
    int* counts  = (int*)(ws + o); o += 32;
    int* offsets = (int*)(ws + o); o += 32;
    int* tok_list = (int*)(ws + o); o += (size_t)NE * T * 4;
    o = (o + 255) & ~(size_t)255;
    int*   sel_e   = (int*)(ws + o); o += (size_t)2 * T * 4;
    int*   sel_pos = (int*)(ws + o); o += (size_t)2 * T * 4;
    float* sel_w   = (float*)(ws + o); o += (size_t)2 * T * 4;
    o = (o + 255) & ~(size_t)255;
    __bf16* xg = (__bf16*)(ws + o);   o += (size_t)(2 * T + 64) * HDIM * 2;
    o = (o + 255) & ~(size_t)255;
    __bf16* Abuf = (__bf16*)(ws + o); o += (size_t)(2 * T + 64) * IDIM * 2;
    o = (o + 255) & ~(size_t)255;
    float* Y = (float*)(ws + o);      o += (size_t)(2 * T + 64) * HDIM * 4;
    o = (o + 255) & ~(size_t)255;
    __bf16* WgT = (__bf16*)(ws + o);  o += (size_t)NE * IDIM * HDIM * 2;
    __bf16* WuT = (__bf16*)(ws + o);  o += (size_t)NE * IDIM * HDIM * 2;
    __bf16* WdT = (__bf16*)(ws + o);  o += (size_t)NE * HDIM * IDIM * 2;

    hipMemsetAsync(counts, 0, 32, stream);

    router_kernel<<<(T + 3) / 4, 256, 0, stream>>>(x, gate_w, counts, tok_list,
                                                   sel_e, sel_pos, sel_w, T);
    prefix_kernel<<<1, 64, 0, stream>>>(counts, offsets);
    gather_x_kernel<<<(2 * T + 3) / 4, 256, 0, stream>>>(x, offsets, tok_list, xg, T);

    transpose_cvt_kernel<<<dim3(IDIM / 64, HDIM / 64, NE), 256, 0, stream>>>(w_gate, WgT, HDIM, IDIM);
    transpose_cvt_kernel<<<dim3(IDIM / 64, HDIM / 64, NE), 256, 0, stream>>>(w_up,   WuT, HDIM, IDIM);
    transpose_cvt_kernel<<<dim3(HDIM / 64, IDIM / 64, NE), 256, 0, stream>>>(w_down, WdT, IDIM, HDIM);

    dim3 gridA((T + 63) / 64, IDIM / 64, NE);
    gateup_mfma_kernel<<<gridA, 256, 0, stream>>>(xg, WgT, WuT, counts, offsets, Abuf, T);

    dim3 gridB((T + 63) / 64, HDIM / 64, NE);
    down_mfma_kernel<<<gridB, 256, 0, stream>>>(Abuf, WdT, counts, offsets, Y, T);

    combine_kernel<<<T, 256, 0, stream>>>(Y, offsets, sel_e, sel_pos, sel_w, out);
}

// Round 7
// 193.711 us; speedup vs baseline: 2.6734x; 1.2478x over previous
//
#include <hip/hip_runtime.h>
#include <hip/hip_bf16.h>

#define HDIM 1024
#define IDIM 768
#define NE   8

typedef __attribute__((ext_vector_type(8))) __bf16 bf16x8;
typedef __attribute__((ext_vector_type(4))) __bf16 bf16x4;
typedef __attribute__((ext_vector_type(4))) float  f32x4;

__device__ __forceinline__ void gload16(const void* g, void* l) {
    __builtin_amdgcn_global_load_lds(
        (const __attribute__((address_space(1))) void*)g,
        (__attribute__((address_space(3))) void*)l, 16, 0, 0);
}

// swizzled element offset within one [64 rows][64 k] bf16 stream tile:
// row r, k-chunk q (16B units, q = ksub*4 + fc) -> slot q ^ (r&7)
__device__ __forceinline__ int swzoff(int r, int j, int fc) {
    return r * 64 + ((((j << 2) + fc) ^ (r & 7)) << 3);
}

// ---------------- Router: logits -> top2 -> renormalized weights ----------------
__global__ __launch_bounds__(256) void router_kernel(
    const float* __restrict__ x, const float* __restrict__ gate_w,
    int* __restrict__ counts, int* __restrict__ tok_list,
    int* __restrict__ sel_e, int* __restrict__ sel_pos, float* __restrict__ sel_w,
    int T)
{
    int wave = (blockIdx.x * blockDim.x + threadIdx.x) >> 6;
    int lane = threadIdx.x & 63;
    if (wave >= T) return;
    const float* xr = x + (size_t)wave * HDIM;

    float acc[NE];
    #pragma unroll
    for (int e = 0; e < NE; ++e) acc[e] = 0.f;

    for (int h = lane; h < HDIM; h += 64) {
        float xv = xr[h];
        const float* g = gate_w + (size_t)h * NE;
        #pragma unroll
        for (int e = 0; e < NE; ++e) acc[e] += xv * g[e];
    }
    #pragma unroll
    for (int e = 0; e < NE; ++e) {
        float v = acc[e];
        #pragma unroll
        for (int s = 32; s > 0; s >>= 1) v += __shfl_xor(v, s);
        acc[e] = v;
    }
    if (lane == 0) {
        int e0 = 0;
        #pragma unroll
        for (int e = 1; e < NE; ++e) if (acc[e] > acc[e0]) e0 = e;
        int e1 = -1;
        #pragma unroll
        for (int e = 0; e < NE; ++e) {
            if (e == e0) continue;
            if (e1 < 0 || acc[e] > acc[e1]) e1 = e;
        }
        float d  = __expf(acc[e1] - acc[e0]);   // <= 1
        float w0 = 1.f / (1.f + d);
        float w1 = 1.f - w0;
        int p0 = atomicAdd(&counts[e0], 1);
        tok_list[e0 * T + p0] = wave;
        int p1 = atomicAdd(&counts[e1], 1);
        tok_list[e1 * T + p1] = wave;
        sel_e[wave * 2 + 0] = e0;  sel_pos[wave * 2 + 0] = p0;  sel_w[wave * 2 + 0] = w0;
        sel_e[wave * 2 + 1] = e1;  sel_pos[wave * 2 + 1] = p1;  sel_w[wave * 2 + 1] = w1;
    }
}

__global__ void prefix_kernel(const int* __restrict__ counts, int* __restrict__ offsets)
{
    if (threadIdx.x == 0 && blockIdx.x == 0) {
        int s = 0;
        for (int e = 0; e < NE; ++e) { offsets[e] = s; s += counts[e]; }
    }
}

// ---------------- Gather x rows into sorted-slot order, fp32 -> bf16 ----------------
__global__ __launch_bounds__(256) void gather_x_kernel(
    const float* __restrict__ x, const int* __restrict__ offsets,
    const int* __restrict__ tok_list, __bf16* __restrict__ xg, int T)
{
    int s = (blockIdx.x * blockDim.x + threadIdx.x) >> 6;
    int lane = threadIdx.x & 63;
    if (s >= 2 * T) return;
    int e = 0;
    #pragma unroll
    for (int k = 1; k < NE; ++k) if (s >= offsets[k]) e = k;
    int pos = s - offsets[e];
    int tok = tok_list[e * T + pos];
    const float* xr = x + (size_t)tok * HDIM;
    __bf16* dr = xg + (size_t)s * HDIM;
    for (int j = lane * 4; j < HDIM; j += 256) {
        float4 v = *(const float4*)&xr[j];
        bf16x4 b;
        b[0] = (__bf16)v.x; b[1] = (__bf16)v.y; b[2] = (__bf16)v.z; b[3] = (__bf16)v.w;
        *(bf16x4*)&dr[j] = b;
    }
}

// ---------------- Fused transpose + convert (all 3 weight tensors, one launch) ----------
// src fp32 [R][C] -> dst bf16 [C][R], per expert. z = mat*8 + e.
__global__ __launch_bounds__(256) void transpose3_kernel(
    const float* __restrict__ wg, const float* __restrict__ wu, const float* __restrict__ wd,
    __bf16* __restrict__ WgT, __bf16* __restrict__ WuT, __bf16* __restrict__ WdT)
{
    int z = blockIdx.z;
    int mat = z >> 3, e = z & 7;
    const float* src; __bf16* dst; int R, C;
    if (mat == 0)      { src = wg; dst = WgT; R = HDIM; C = IDIM; }
    else if (mat == 1) { src = wu; dst = WuT; R = HDIM; C = IDIM; }
    else               { src = wd; dst = WdT; R = IDIM; C = HDIM; }
    int c0 = blockIdx.x * 64, r0 = blockIdx.y * 64;
    if (c0 >= C || r0 >= R) return;
    src += (size_t)e * R * C;
    dst += (size_t)e * R * C;

    __shared__ __bf16 Lt[64][72];   // [c][r], padded
    int t = threadIdx.x;
    int rin = t >> 4, c4 = (t & 15) * 4;
    #pragma unroll
    for (int rr = 0; rr < 4; ++rr) {
        int r = rr * 16 + rin;
        float4 v = *(const float4*)&src[(size_t)(r0 + r) * C + c0 + c4];
        Lt[c4 + 0][r] = (__bf16)v.x; Lt[c4 + 1][r] = (__bf16)v.y;
        Lt[c4 + 2][r] = (__bf16)v.z; Lt[c4 + 3][r] = (__bf16)v.w;
    }
    __syncthreads();
    int c = t >> 4, r4 = (t & 15) * 4;
    #pragma unroll
    for (int j = 0; j < 4; ++j) {
        int cc = c + j * 16;
        bf16x4 v = *(bf16x4*)&Lt[cc][r4];
        *(bf16x4*)&dst[(size_t)(c0 + cc) * R + r0 + r4] = v;
    }
}

// ---------------- Gate+Up MFMA: BK=64, ring-3, XCD-swizzled 1D grid ----------------
// grid = nx*12*8; e = bid&7 (expert-per-XCD), rem = bid>>3, x_t = rem%nx, i_t = rem/nx.
__global__ __launch_bounds__(256) void gateup_mfma_kernel(
    const __bf16* __restrict__ xg,
    const __bf16* __restrict__ WgT, const __bf16* __restrict__ WuT,
    const int* __restrict__ counts, const int* __restrict__ offsets,
    __bf16* __restrict__ Abuf, int T, int nx)
{
    int bid = blockIdx.x;
    int e = bid & 7;
    int rem = bid >> 3;
    int x_t = rem % nx, i_t = rem / nx;
    int n = counts[e];
    int t0 = x_t * 64;
    if (t0 >= n) return;
    int i0 = i_t * 64;
    int base = offsets[e];

    __shared__ __bf16 lds[3 * 3 * 4096];   // 3 bufs x {G,U,X} x 8KB = 72 KB

    int tid = threadIdx.x;
    int w = tid >> 6, lane = tid & 63;
    int wr = w >> 1, wc = w & 1;

    const __bf16* gW = WgT + (size_t)e * IDIM * HDIM;
    const __bf16* uW = WuT + (size_t)e * IDIM * HDIM;
    const __bf16* xS = xg + (size_t)(base + t0) * HDIM;

    // staging: wave w covers rows w*16..w*16+15; per gload g: row = w*16+g*8+(lane>>3),
    // source chunk pre-swizzled (lane&7)^(row&7) so linear LDS dest = swizzled tile.
    int sr0 = w * 16 + (lane >> 3);
    int sr1 = sr0 + 8;
    int sc0 = ((lane & 7) ^ (sr0 & 7)) * 8;
    int sc1 = ((lane & 7) ^ (sr1 & 7)) * 8;
    const __bf16* gp0 = gW + (size_t)(i0 + sr0) * HDIM + sc0;
    const __bf16* gp1 = gW + (size_t)(i0 + sr1) * HDIM + sc1;
    const __bf16* up0 = uW + (size_t)(i0 + sr0) * HDIM + sc0;
    const __bf16* up1 = uW + (size_t)(i0 + sr1) * HDIM + sc1;
    const __bf16* xp0 = xS + (size_t)sr0 * HDIM + sc0;
    const __bf16* xp1 = xS + (size_t)sr1 * HDIM + sc1;
    int dbase = w * 1024;

#define STAGE_GU(buf, kt) { \
    int k0 = (kt) * 64; \
    __bf16* L = lds + (buf) * 12288; \
    gload16(gp0 + k0, L + dbase);                  \
    gload16(gp1 + k0, L + dbase + 512);            \
    gload16(up0 + k0, L + 4096 + dbase);           \
    gload16(up1 + k0, L + 4096 + dbase + 512);     \
    gload16(xp0 + k0, L + 8192 + dbase);           \
    gload16(xp1 + k0, L + 8192 + dbase + 512);     \
}

    f32x4 accg[2][2], accu[2][2];
    #pragma unroll
    for (int a = 0; a < 2; ++a)
        #pragma unroll
        for (int b = 0; b < 2; ++b) { accg[a][b] = (f32x4)0.f; accu[a][b] = (f32x4)0.f; }

    int fr = lane & 15, fc = lane >> 4;
    int ra0 = wc * 32 + fr,  ra1 = ra0 + 16;   // weight (i) rows
    int rb0 = wr * 32 + fr,  rb1 = rb0 + 16;   // slot rows
    int oA0[2] = { swzoff(ra0, 0, fc), swzoff(ra0, 1, fc) };
    int oA1[2] = { swzoff(ra1, 0, fc), swzoff(ra1, 1, fc) };
    int oB0[2] = { swzoff(rb0, 0, fc), swzoff(rb0, 1, fc) };
    int oB1[2] = { swzoff(rb1, 0, fc), swzoff(rb1, 1, fc) };

    const int NK = HDIM / 64;   // 16
    STAGE_GU(0, 0);
    STAGE_GU(1, 1);

    for (int kt = 0; kt < NK; ++kt) {
        if (kt < NK - 1) asm volatile("s_waitcnt vmcnt(6)" ::: "memory");
        else             asm volatile("s_waitcnt vmcnt(0)" ::: "memory");
        __builtin_amdgcn_s_barrier();
        if (kt + 2 < NK) STAGE_GU((kt + 2) % 3, kt + 2);
        const __bf16* L  = lds + (kt % 3) * 12288;
        const __bf16* Lg = L;
        const __bf16* Lu = L + 4096;
        const __bf16* Lx = L + 8192;
        #pragma unroll
        for (int j = 0; j < 2; ++j) {
            bf16x8 ag0 = *(const bf16x8*)(Lg + oA0[j]);
            bf16x8 ag1 = *(const bf16x8*)(Lg + oA1[j]);
            bf16x8 au0 = *(const bf16x8*)(Lu + oA0[j]);
            bf16x8 au1 = *(const bf16x8*)(Lu + oA1[j]);
            bf16x8 bx0 = *(const bf16x8*)(Lx + oB0[j]);
            bf16x8 bx1 = *(const bf16x8*)(Lx + oB1[j]);
            accg[0][0] = __builtin_amdgcn_mfma_f32_16x16x32_bf16(ag0, bx0, accg[0][0], 0, 0, 0);
            accg[0][1] = __builtin_amdgcn_mfma_f32_16x16x32_bf16(ag1, bx0, accg[0][1], 0, 0, 0);
            accg[1][0] = __builtin_amdgcn_mfma_f32_16x16x32_bf16(ag0, bx1, accg[1][0], 0, 0, 0);
            accg[1][1] = __builtin_amdgcn_mfma_f32_16x16x32_bf16(ag1, bx1, accg[1][1], 0, 0, 0);
            accu[0][0] = __builtin_amdgcn_mfma_f32_16x16x32_bf16(au0, bx0, accu[0][0], 0, 0, 0);
            accu[0][1] = __builtin_amdgcn_mfma_f32_16x16x32_bf16(au1, bx0, accu[0][1], 0, 0, 0);
            accu[1][0] = __builtin_amdgcn_mfma_f32_16x16x32_bf16(au0, bx1, accu[1][0], 0, 0, 0);
            accu[1][1] = __builtin_amdgcn_mfma_f32_16x16x32_bf16(au1, bx1, accu[1][1], 0, 0, 0);
        }
    }
#undef STAGE_GU

    // D: col = lane&15 = slot, row = (lane>>4)*4+reg = i
    int dr4 = (lane >> 4) * 4;
    #pragma unroll
    for (int ti = 0; ti < 2; ++ti) {
        int tl = wr * 32 + ti * 16 + fr;
        if (t0 + tl < n) {
            size_t slotrow = (size_t)(base + t0 + tl) * IDIM;
            #pragma unroll
            for (int ii = 0; ii < 2; ++ii) {
                f32x4 g = accg[ti][ii], u = accu[ti][ii];
                bf16x4 o;
                #pragma unroll
                for (int r = 0; r < 4; ++r) {
                    float gv = g[r];
                    float s = gv / (1.f + __expf(-gv));
                    o[r] = (__bf16)(s * u[r]);
                }
                *(bf16x4*)&Abuf[slotrow + i0 + wc * 32 + ii * 16 + dr4] = o;
            }
        }
    }
}

// ---------------- Down MFMA: BK=64, ring-3, XCD-swizzled; Y[slot][h] fp32 ----------------
// grid = nx*16*8; e = bid&7, rem = bid>>3, x_t = rem%nx, h_t = rem/nx.
__global__ __launch_bounds__(256) void down_mfma_kernel(
    const __bf16* __restrict__ Abuf, const __bf16* __restrict__ WdT,
    const int* __restrict__ counts, const int* __restrict__ offsets,
    float* __restrict__ Y, int T, int nx)
{
    int bid = blockIdx.x;
    int e = bid & 7;
    int rem = bid >> 3;
    int x_t = rem % nx, h_t = rem / nx;
    int n = counts[e];
    int t0 = x_t * 64;
    if (t0 >= n) return;
    int h0 = h_t * 64;
    int base = offsets[e];

    __shared__ __bf16 lds[3 * 2 * 4096];   // 3 bufs x {W,A} x 8KB = 48 KB

    int tid = threadIdx.x;
    int w = tid >> 6, lane = tid & 63;
    int wr = w >> 1, wc = w & 1;

    const __bf16* dW = WdT + (size_t)e * HDIM * IDIM;   // [H][I]
    const __bf16* aS = Abuf + (size_t)(base + t0) * IDIM;

    int sr0 = w * 16 + (lane >> 3);
    int sr1 = sr0 + 8;
    int sc0 = ((lane & 7) ^ (sr0 & 7)) * 8;
    int sc1 = ((lane & 7) ^ (sr1 & 7)) * 8;
    const __bf16* wp0 = dW + (size_t)(h0 + sr0) * IDIM + sc0;
    const __bf16* wp1 = dW + (size_t)(h0 + sr1) * IDIM + sc1;
    const __bf16* ap0 = aS + (size_t)sr0 * IDIM + sc0;
    const __bf16* ap1 = aS + (size_t)sr1 * IDIM + sc1;
    int dbase = w * 1024;

#define STAGE_D(buf, kt) { \
    int k0 = (kt) * 64; \
    __bf16* L = lds + (buf) * 8192; \
    gload16(wp0 + k0, L + dbase);              \
    gload16(wp1 + k0, L + dbase + 512);        \
    gload16(ap0 + k0, L + 4096 + dbase);       \
    gload16(ap1 + k0, L + 4096 + dbase + 512); \
}

    f32x4 acc[2][2];
    #pragma unroll
    for (int a = 0; a < 2; ++a)
        #pragma unroll
        for (int b = 0; b < 2; ++b) acc[a][b] = (f32x4)0.f;

    int fr = lane & 15, fc = lane >> 4;
    int ra0 = wc * 32 + fr,  ra1 = ra0 + 16;   // h rows
    int rb0 = wr * 32 + fr,  rb1 = rb0 + 16;   // slot rows
    int oA0[2] = { swzoff(ra0, 0, fc), swzoff(ra0, 1, fc) };
    int oA1[2] = { swzoff(ra1, 0, fc), swzoff(ra1, 1, fc) };
    int oB0[2] = { swzoff(rb0, 0, fc), swzoff(rb0, 1, fc) };
    int oB1[2] = { swzoff(rb1, 0, fc), swzoff(rb1, 1, fc) };

    const int NK = IDIM / 64;   // 12
    STAGE_D(0, 0);
    STAGE_D(1, 1);

    for (int kt = 0; kt < NK; ++kt) {
        if (kt < NK - 1) asm volatile("s_waitcnt vmcnt(4)" ::: "memory");
        else             asm volatile("s_waitcnt vmcnt(0)" ::: "memory");
        __builtin_amdgcn_s_barrier();
        if (kt + 2 < NK) STAGE_D((kt + 2) % 3, kt + 2);
        const __bf16* L  = lds + (kt % 3) * 8192;
        const __bf16* Lw = L;
        const __bf16* La = L + 4096;
        #pragma unroll
        for (int j = 0; j < 2; ++j) {
            bf16x8 aw0 = *(const bf16x8*)(Lw + oA0[j]);
            bf16x8 aw1 = *(const bf16x8*)(Lw + oA1[j]);
            bf16x8 ab0 = *(const bf16x8*)(La + oB0[j]);
            bf16x8 ab1 = *(const bf16x8*)(La + oB1[j]);
            acc[0][0] = __builtin_amdgcn_mfma_f32_16x16x32_bf16(aw0, ab0, acc[0][0], 0, 0, 0);
            acc[0][1] = __builtin_amdgcn_mfma_f32_16x16x32_bf16(aw1, ab0, acc[0][1], 0, 0, 0);
            acc[1][0] = __builtin_amdgcn_mfma_f32_16x16x32_bf16(aw0, ab1, acc[1][0], 0, 0, 0);
            acc[1][1] = __builtin_amdgcn_mfma_f32_16x16x32_bf16(aw1, ab1, acc[1][1], 0, 0, 0);
        }
    }
#undef STAGE_D

    int dr4 = (lane >> 4) * 4;
    #pragma unroll
    for (int si = 0; si < 2; ++si) {
        int sl = wr * 32 + si * 16 + fr;
        if (t0 + sl < n) {
            float* yrow = Y + (size_t)(base + t0 + sl) * HDIM + h0;
            #pragma unroll
            for (int hi = 0; hi < 2; ++hi) {
                f32x4 a = acc[si][hi];
                *(f32x4*)&yrow[wc * 32 + hi * 16 + dr4] = a;
            }
        }
    }
}

// ---------------- Combine: out[t] = w0*Y[s0] + w1*Y[s1] ----------------
__global__ __launch_bounds__(256) void combine_kernel(
    const float* __restrict__ Y, const int* __restrict__ offsets,
    const int* __restrict__ sel_e, const int* __restrict__ sel_pos,
    const float* __restrict__ sel_w, float* __restrict__ out)
{
    int t = blockIdx.x;
    int h4 = threadIdx.x * 4;            // 256 threads * 4 = 1024 = HDIM
    int s0 = offsets[sel_e[t * 2 + 0]] + sel_pos[t * 2 + 0];
    int s1 = offsets[sel_e[t * 2 + 1]] + sel_pos[t * 2 + 1];
    float w0 = sel_w[t * 2 + 0], w1 = sel_w[t * 2 + 1];
    float4 a = *(const float4*)&Y[(size_t)s0 * HDIM + h4];
    float4 b = *(const float4*)&Y[(size_t)s1 * HDIM + h4];
    float4 o;
    o.x = w0 * a.x + w1 * b.x;  o.y = w0 * a.y + w1 * b.y;
    o.z = w0 * a.z + w1 * b.z;  o.w = w0 * a.w + w1 * b.w;
    *(float4*)&out[(size_t)t * HDIM + h4] = o;
}

extern "C" void kernel_launch(void* const* d_in, const int* in_sizes, int n_in,
                              void* d_out, int out_size, void* d_ws, size_t ws_size,
                              hipStream_t stream)
{
    const float* x      = (const float*)d_in[0];
    const float* gate_w = (const float*)d_in[1];
    const float* w_gate = (const float*)d_in[2];
    const float* w_up   = (const float*)d_in[3];
    const float* w_down = (const float*)d_in[4];
    float* out = (float*)d_out;

    int T = in_sizes[0] / HDIM;
    int nx = (T + 63) / 64;

    // Workspace layout (bytes), 256-aligned sections
    char* ws = (char*)d_ws;
    size_t o = 0;
    int* counts  = (int*)(ws + o); o += 32;
    int* offsets = (int*)(ws + o); o += 32;
    int* tok_list = (int*)(ws + o); o += (size_t)NE * T * 4;
    o = (o + 255) & ~(size_t)255;
    int*   sel_e   = (int*)(ws + o); o += (size_t)2 * T * 4;
    int*   sel_pos = (int*)(ws + o); o += (size_t)2 * T * 4;
    float* sel_w   = (float*)(ws + o); o += (size_t)2 * T * 4;
    o = (o + 255) & ~(size_t)255;
    __bf16* xg = (__bf16*)(ws + o);   o += (size_t)(2 * T + 64) * HDIM * 2;
    o = (o + 255) & ~(size_t)255;
    __bf16* Abuf = (__bf16*)(ws + o); o += (size_t)(2 * T + 64) * IDIM * 2;
    o = (o + 255) & ~(size_t)255;
    float* Y = (float*)(ws + o);      o += (size_t)(2 * T + 64) * HDIM * 4;
    o = (o + 255) & ~(size_t)255;
    __bf16* WgT = (__bf16*)(ws + o);  o += (size_t)NE * IDIM * HDIM * 2;
    __bf16* WuT = (__bf16*)(ws + o);  o += (size_t)NE * IDIM * HDIM * 2;
    __bf16* WdT = (__bf16*)(ws + o);  o += (size_t)NE * HDIM * IDIM * 2;

    hipMemsetAsync(counts, 0, 32, stream);

    router_kernel<<<(T + 3) / 4, 256, 0, stream>>>(x, gate_w, counts, tok_list,
                                                   sel_e, sel_pos, sel_w, T);
    prefix_kernel<<<1, 64, 0, stream>>>(counts, offsets);
    gather_x_kernel<<<(2 * T + 3) / 4, 256, 0, stream>>>(x, offsets, tok_list, xg, T);

    transpose3_kernel<<<dim3(16, 16, 24), 256, 0, stream>>>(w_gate, w_up, w_down,
                                                            WgT, WuT, WdT);

    gateup_mfma_kernel<<<nx * (IDIM / 64) * NE, 256, 0, stream>>>(
        xg, WgT, WuT, counts, offsets, Abuf, T, nx);

    down_mfma_kernel<<<nx * (HDIM / 64) * NE, 256, 0, stream>>>(
        Abuf, WdT, counts, offsets, Y, T, nx);

    combine_kernel<<<T, 256, 0, stream>>>(Y, offsets, sel_e, sel_pos, sel_w, out);
}